// Round 7
// baseline (156.890 us; speedup 1.0000x reference)
//
#include <hip/hip_runtime.h>
#include <math.h>

// SoftVoxelOccupancyVFE: per-voxel masked mean/var of xyz + tiny MLP + sigmoid.
// N=200000 voxels, M=32 points, C=4 channels interleaved. Memory-bound
// (102.4 MB fetch floor ~= 16.3 us @ ~6.3 TB/s achievable).
// Layout (R4 structure): 4 lanes per voxel, each lane loads 8 points as
// independent float4 loads; one-pass variance via E[x^2]-mean^2 -> single
// 2-level shuffle reduction. R7 delta: REMOVED __builtin_nontemporal_load —
// theory: nt/no-allocate on 64 B-segment requests (TCC line = 128 B) causes
// the adjacent instruction's other 64 B half-line to re-miss -> ~2x HBM fetch
// (est. 29 us kernel vs 16 us floor). Plain loads let L2 serve the second
// half-line.

typedef float floatx4 __attribute__((ext_vector_type(4)));

#define LANES_PER_VOX 4
#define VOX_PER_BLOCK 64   // 256 threads / 4 lanes-per-voxel

__global__ __launch_bounds__(256, 8) void vfe_kernel(
    const floatx4* __restrict__ feats,     // N*32 float4 (x,y,z,w)
    const int*    __restrict__ num_points, // N
    const float*  __restrict__ W1,         // 5x16 row-major
    const float*  __restrict__ b1,         // 16
    const float*  __restrict__ W2,         // 16x1
    const float*  __restrict__ b2,         // 1
    float*        __restrict__ out,        // N
    int N)
{
    __shared__ float sW1[80];
    __shared__ float sb1[16];
    __shared__ float sW2[16];
    __shared__ float sb2;

    const int t = threadIdx.x;
    if (t < 80) sW1[t] = W1[t];
    if (t < 16) { sb1[t] = b1[t]; sW2[t] = W2[t]; }
    if (t == 0) sb2 = b2[0];
    __syncthreads();

    const int j   = t & 3;                 // lane within voxel group (0..3)
    const int vox = blockIdx.x * VOX_PER_BLOCK + (t >> 2);
    if (vox >= N) return;

    const int   np        = num_points[vox];
    const float npf       = (float)np;
    const float inv_denom = 1.0f / fmaxf(npf, 1.0f);

    // 8 independent 16 B loads per lane; group of 4 lanes covers one
    // contiguous 64 B segment per load instruction (plain loads -> L2
    // allocate, second half of each 128 B line served from L2).
    const floatx4* vbase = feats + (size_t)vox * 32;
    floatx4 f[8];
    #pragma unroll
    for (int i = 0; i < 8; ++i)
        f[i] = vbase[j + 4 * i];

    // local masked partials
    float sx = 0.0f, sy = 0.0f, sz = 0.0f, sq = 0.0f;
    #pragma unroll
    for (int i = 0; i < 8; ++i) {
        const float m = (j + 4 * i < np) ? 1.0f : 0.0f;
        sx += f[i].x * m;
        sy += f[i].y * m;
        sz += f[i].z * m;
        sq += m * (f[i].x * f[i].x + f[i].y * f[i].y + f[i].z * f[i].z);
    }

    // single 2-level reduction over the 4-lane group (xor masks stay in-group)
    #pragma unroll
    for (int d = 1; d <= 2; d <<= 1) {
        sx += __shfl_xor(sx, d);
        sy += __shfl_xor(sy, d);
        sz += __shfl_xor(sz, d);
        sq += __shfl_xor(sq, d);
    }

    const float mean_x = sx * inv_denom;
    const float mean_y = sy * inv_denom;
    const float mean_z = sz * inv_denom;

    // sum m*(x-mx)^2 etc = sq - (sx^2+sy^2+sz^2)/denom  (exact; 0 for np=0)
    float qtot = sq - (sx * sx + sy * sy + sz * sz) * inv_denom;
    float var_mean = fmaxf(qtot, 0.0f) * inv_denom * (1.0f / 3.0f);

    const float p_var     = __expf(-0.5f * var_mean);
    const float p_density = fminf(npf, 10.0f) * 0.1f;

    // MLP: lane j computes hidden units j, j+4, j+8, j+12; 2-level reduce
    float c = 0.0f;
    #pragma unroll
    for (int u0 = 0; u0 < 16; u0 += 4) {
        const int u = u0 + j;
        float h = sb1[u]
                + p_density * sW1[u]
                + p_var     * sW1[16 + u]
                + mean_x    * sW1[32 + u]
                + mean_y    * sW1[48 + u]
                + mean_z    * sW1[64 + u];
        c += fmaxf(h, 0.0f) * sW2[u];
    }
    c += __shfl_xor(c, 1);
    c += __shfl_xor(c, 2);

    if (j == 0) {
        const float logit = c + sb2;
        out[vox] = 1.0f / (1.0f + __expf(-logit));
    }
}

extern "C" void kernel_launch(void* const* d_in, const int* in_sizes, int n_in,
                              void* d_out, int out_size, void* d_ws, size_t ws_size,
                              hipStream_t stream) {
    // setup_inputs order: features, num_points, coors, W1, b1, W2, b2
    const floatx4* feats     = (const floatx4*)d_in[0];
    const int*    num_points = (const int*)d_in[1];
    // d_in[2] = coors (unused by the reference)
    const float*  W1 = (const float*)d_in[3];
    const float*  b1 = (const float*)d_in[4];
    const float*  W2 = (const float*)d_in[5];
    const float*  b2 = (const float*)d_in[6];
    float* out = (float*)d_out;

    const int N = in_sizes[1];                 // 200000
    const int blocks = (N + VOX_PER_BLOCK - 1) / VOX_PER_BLOCK;
    vfe_kernel<<<blocks, 256, 0, stream>>>(feats, num_points, W1, b1, W2, b2, out, N);
}

// Round 8
// 152.131 us; speedup vs baseline: 1.0313x; 1.0313x over previous
//
#include <hip/hip_runtime.h>
#include <math.h>

// SoftVoxelOccupancyVFE: per-voxel masked mean/var of xyz + tiny MLP + sigmoid.
// N=200000 voxels, M=32 points, C=4 channels interleaved. Memory-bound
// (102.4 MB fetch floor ~= 16 us @ ~6.5 TB/s achievable).
// R8: 8 lanes per voxel, 4 nt float4 loads per lane. Each load instruction
// covers a FULL 128 B cache line per group (lanes j=0..7 -> points 8i..8i+7),
// line-aligned, so nt/no-allocate cannot cause half-line re-fetch; nt skips
// L2 allocation on this pure stream (measured: nt helped on 64 B segments,
// R4 150.9 vs R7 156.9). One-pass variance via E[x^2]-mean^2. No min-waves
// launch bound (R6 suggested it cost ~3 us vs R4).

typedef float floatx4 __attribute__((ext_vector_type(4)));

#define LANES_PER_VOX 8
#define VOX_PER_BLOCK 32   // 256 threads / 8 lanes-per-voxel

__global__ __launch_bounds__(256) void vfe_kernel(
    const floatx4* __restrict__ feats,     // N*32 float4 (x,y,z,w)
    const int*    __restrict__ num_points, // N
    const float*  __restrict__ W1,         // 5x16 row-major
    const float*  __restrict__ b1,         // 16
    const float*  __restrict__ W2,         // 16x1
    const float*  __restrict__ b2,         // 1
    float*        __restrict__ out,        // N
    int N)
{
    __shared__ float sW1[80];
    __shared__ float sb1[16];
    __shared__ float sW2[16];
    __shared__ float sb2;

    const int t = threadIdx.x;
    if (t < 80) sW1[t] = W1[t];
    if (t < 16) { sb1[t] = b1[t]; sW2[t] = W2[t]; }
    if (t == 0) sb2 = b2[0];
    __syncthreads();

    const int j   = t & 7;                 // lane within voxel group (0..7)
    const int vox = blockIdx.x * VOX_PER_BLOCK + (t >> 3);
    if (vox >= N) return;

    const int   np        = num_points[vox];
    const float npf       = (float)np;
    const float inv_denom = 1.0f / fmaxf(npf, 1.0f);

    // 4 independent nt 16 B loads; instruction i covers points 8i..8i+7 of
    // each voxel -> one aligned 128 B line per 8-lane group per instruction.
    const floatx4* vbase = feats + (size_t)vox * 32;
    floatx4 f[4];
    #pragma unroll
    for (int i = 0; i < 4; ++i)
        f[i] = __builtin_nontemporal_load(&vbase[j + 8 * i]);

    // local masked partials
    float sx = 0.0f, sy = 0.0f, sz = 0.0f, sq = 0.0f;
    #pragma unroll
    for (int i = 0; i < 4; ++i) {
        const float m = (j + 8 * i < np) ? 1.0f : 0.0f;
        sx += f[i].x * m;
        sy += f[i].y * m;
        sz += f[i].z * m;
        sq += m * (f[i].x * f[i].x + f[i].y * f[i].y + f[i].z * f[i].z);
    }

    // single 3-level reduction over the 8-lane group (xor masks stay in-group)
    #pragma unroll
    for (int d = 1; d <= 4; d <<= 1) {
        sx += __shfl_xor(sx, d);
        sy += __shfl_xor(sy, d);
        sz += __shfl_xor(sz, d);
        sq += __shfl_xor(sq, d);
    }

    const float mean_x = sx * inv_denom;
    const float mean_y = sy * inv_denom;
    const float mean_z = sz * inv_denom;

    // sum m*(x-mx)^2 etc = sq - (sx^2+sy^2+sz^2)/denom  (exact; 0 for np=0)
    float qtot = sq - (sx * sx + sy * sy + sz * sz) * inv_denom;
    float var_mean = fmaxf(qtot, 0.0f) * inv_denom * (1.0f / 3.0f);

    const float p_var     = __expf(-0.5f * var_mean);
    const float p_density = fminf(npf, 10.0f) * 0.1f;

    // MLP: lane j computes hidden units j and j+8, then 3-level reduce
    float c = 0.0f;
    #pragma unroll
    for (int u0 = 0; u0 < 16; u0 += 8) {
        const int u = u0 + j;
        float h = sb1[u]
                + p_density * sW1[u]
                + p_var     * sW1[16 + u]
                + mean_x    * sW1[32 + u]
                + mean_y    * sW1[48 + u]
                + mean_z    * sW1[64 + u];
        c += fmaxf(h, 0.0f) * sW2[u];
    }
    c += __shfl_xor(c, 1);
    c += __shfl_xor(c, 2);
    c += __shfl_xor(c, 4);

    if (j == 0) {
        const float logit = c + sb2;
        out[vox] = 1.0f / (1.0f + __expf(-logit));
    }
}

extern "C" void kernel_launch(void* const* d_in, const int* in_sizes, int n_in,
                              void* d_out, int out_size, void* d_ws, size_t ws_size,
                              hipStream_t stream) {
    // setup_inputs order: features, num_points, coors, W1, b1, W2, b2
    const floatx4* feats     = (const floatx4*)d_in[0];
    const int*    num_points = (const int*)d_in[1];
    // d_in[2] = coors (unused by the reference)
    const float*  W1 = (const float*)d_in[3];
    const float*  b1 = (const float*)d_in[4];
    const float*  W2 = (const float*)d_in[5];
    const float*  b2 = (const float*)d_in[6];
    float* out = (float*)d_out;

    const int N = in_sizes[1];                 // 200000
    const int blocks = (N + VOX_PER_BLOCK - 1) / VOX_PER_BLOCK;
    vfe_kernel<<<blocks, 256, 0, stream>>>(feats, num_points, W1, b1, W2, b2, out, N);
}